// Round 1
// baseline (108.644 us; speedup 1.0000x reference)
//
#include <hip/hip_runtime.h>
#include <hip/hip_bf16.h>

#define HH 64
#define TT 128
#define BT 16

typedef __attribute__((ext_vector_type(8))) short bf16x8;
typedef __attribute__((ext_vector_type(4))) float f32x4;

__device__ __forceinline__ unsigned short f2bf(float f) {
  union { float f; unsigned u; } v; v.f = f;
  return (unsigned short)((v.u + 0x7FFFu + ((v.u >> 16) & 1u)) >> 16);
}
__device__ __forceinline__ float sigm(float x) {
  return __builtin_amdgcn_rcpf(1.f + __builtin_amdgcn_exp2f(-1.44269504f * x));
}
__device__ __forceinline__ float tanh_(float x) {
  x = fminf(fmaxf(x, -15.f), 15.f);
  float e = __builtin_amdgcn_exp2f(2.88539008f * x);
  return (e - 1.f) * __builtin_amdgcn_rcpf(e + 1.f);
}
__device__ __forceinline__ float wred64(float v) {
#pragma unroll
  for (int s = 32; s; s >>= 1) v += __shfl_xor(v, s);
  return v;
}

// ---------- kernel 1: embed fp32 -> bf16 ----------
__global__ void convert_embed(const float* __restrict__ src,
                              unsigned short* __restrict__ dst, int n) {
  int base = (blockIdx.x * 256 + threadIdx.x) * 4;
  if (base + 4 <= n) {
    float4 v = *(const float4*)(src + base);
    ushort4 r;
    r.x = f2bf(v.x); r.y = f2bf(v.y); r.z = f2bf(v.z); r.w = f2bf(v.w);
    *(ushort4*)(dst + base) = r;
  } else {
    for (int k = base; k < n; k++) dst[k] = f2bf(src[k]);
  }
}

#define MFMA(acc, a, b) acc = __builtin_amdgcn_mfma_f32_16x16x32_bf16(a, b, acc, 0, 0, 0)

// ---------- kernel 2: fused LSTM over T=128 ----------
__global__ __launch_bounds__(256, 1) void lstm_k(
    const int* __restrict__ inst, const unsigned short* __restrict__ ebf,
    const float* __restrict__ Wih, const float* __restrict__ Whh,
    const float* __restrict__ bih, const float* __restrict__ bhh,
    float* __restrict__ hbuf)
{
  __shared__ int tokT[TT * BT];                 // [t][b_local]
  __shared__ unsigned short hsh[2 * BT * HH];   // double-buffered h, bf16, XOR-swizzled

  const int tid  = threadIdx.x;
  const int lane = tid & 63;
  const int w    = tid >> 6;     // wave id 0..3, owns n-tiles {w, w+4, w+8, w+12}
  const int fr   = lane & 15;
  const int fg   = lane >> 4;
  const int b0   = blockIdx.x * BT;
  const int jcol = w * 16 + fr;  // hidden index this lane produces

  for (int i = tid; i < BT * TT; i += 256)
    tokT[(i & (TT - 1)) * BT + (i >> 7)] = inst[b0 * TT + i];
  for (int i = tid; i < BT * HH; i += 256) hsh[i] = 0;

  // W fragments in registers (stay for whole kernel): B-operand layout
  // B[k][n] = W[n][k], lane holds n = n0+(lane&15), k = kt*32 + (lane>>4)*8 + j
  bf16x8 wih[4][2], whh[4][2];
  float bias[4];
#pragma unroll
  for (int q = 0; q < 4; q++) {
    const int n = (w + q * 4) * 16 + fr;
    bias[q] = bih[n] + bhh[n];
#pragma unroll
    for (int kt = 0; kt < 2; kt++) {
      const float* pa = Wih + n * 64 + kt * 32 + fg * 8;
      const float* pb = Whh + n * 64 + kt * 32 + fg * 8;
      bf16x8 fa, fb;
#pragma unroll
      for (int j = 0; j < 8; j++) { fa[j] = (short)f2bf(pa[j]); fb[j] = (short)f2bf(pb[j]); }
      wih[q][kt] = fa; whh[q][kt] = fb;
    }
  }

  __syncthreads();

  // prefetch x fragments for t=0: A[m][k], lane: m=fr, k = fg*8.. (16B contiguous)
  bf16x8 xa0, xa1;
  {
    const int tk = tokT[0 * BT + fr];
    const unsigned short* p = ebf + tk * 64 + fg * 8;
    xa0 = *(const bf16x8*)p;
    xa1 = *(const bf16x8*)(p + 32);
  }

  float cst[4] = {0.f, 0.f, 0.f, 0.f};
  float hkeep[4] = {0.f, 0.f, 0.f, 0.f};

  for (int t = 0; t < TT; t++) {
    // prefetch next step's x
    bf16x8 xn0 = xa0, xn1 = xa1;
    if (t + 1 < TT) {
      const int tk = tokT[(t + 1) * BT + fr];
      const unsigned short* p = ebf + tk * 64 + fg * 8;
      xn0 = *(const bf16x8*)p;
      xn1 = *(const bf16x8*)(p + 32);
    }

    // h fragments from LDS (swizzled)
    const char* hb = (const char*)hsh + (t & 1) * (BT * HH * 2);
    const int sx = (fr & 7) << 4;
    bf16x8 ha0 = *(const bf16x8*)(hb + ((fr * 128 + fg * 16) ^ sx));
    bf16x8 ha1 = *(const bf16x8*)(hb + ((fr * 128 + 64 + fg * 16) ^ sx));

    f32x4 D0 = {0.f,0.f,0.f,0.f}, D1 = {0.f,0.f,0.f,0.f},
          D2 = {0.f,0.f,0.f,0.f}, D3 = {0.f,0.f,0.f,0.f};
    MFMA(D0, xa0, wih[0][0]); MFMA(D0, xa1, wih[0][1]);
    MFMA(D1, xa0, wih[1][0]); MFMA(D1, xa1, wih[1][1]);
    MFMA(D2, xa0, wih[2][0]); MFMA(D2, xa1, wih[2][1]);
    MFMA(D3, xa0, wih[3][0]); MFMA(D3, xa1, wih[3][1]);
    MFMA(D0, ha0, whh[0][0]); MFMA(D0, ha1, whh[0][1]);
    MFMA(D1, ha0, whh[1][0]); MFMA(D1, ha1, whh[1][1]);
    MFMA(D2, ha0, whh[2][0]); MFMA(D2, ha1, whh[2][1]);
    MFMA(D3, ha0, whh[3][0]); MFMA(D3, ha1, whh[3][1]);

    // cell update: lane owns (m = fg*4+r, j = jcol) for r=0..3; i,f,g,o all in-lane
    char* hwb = (char*)hsh + ((t + 1) & 1) * (BT * HH * 2);
#pragma unroll
    for (int r = 0; r < 4; r++) {
      const float gi = sigm(D0[r] + bias[0]);
      const float gf = sigm(D1[r] + bias[1]);
      const float gg = tanh_(D2[r] + bias[2]);
      const float go = sigm(D3[r] + bias[3]);
      const float cn = gf * cst[r] + gi * gg;
      cst[r] = cn;
      const float hn = go * tanh_(cn);
      hkeep[r] = hn;
      const int m = fg * 4 + r;
      *(unsigned short*)(hwb + ((m * 128 + 2 * jcol) ^ ((m & 7) << 4))) = f2bf(hn);
    }
    __syncthreads();
    xa0 = xn0; xa1 = xn1;
  }

#pragma unroll
  for (int r = 0; r < 4; r++) {
    const int m = fg * 4 + r;
    hbuf[(size_t)(b0 + m) * 64 + jcol] = hkeep[r];
  }
}

// ---------- kernel 3: pointer head + output heads (1 wave / batch row) ----------
__global__ __launch_bounds__(256, 2) void head_k(
    const int* __restrict__ inst, const float* __restrict__ canvas,
    const float* __restrict__ hbuf,
    const float* __restrict__ Wc, const float* __restrict__ bc,
    const float* __restrict__ Ws, const float* __restrict__ bs,
    const float* __restrict__ Wo, const float* __restrict__ bo,
    const float* __restrict__ Wr1, const float* __restrict__ br1,
    const float* __restrict__ Wr2, const float* __restrict__ br2,
    float* __restrict__ out, int B)
{
  __shared__ float Wr1_s[32 * 69];
  __shared__ float h_s[4][64];
  __shared__ float cv_s[4][100];
  __shared__ float sc_s[4][25];

  const int tid = threadIdx.x, lane = tid & 63, w = tid >> 6;
  const int b = blockIdx.x * 4 + w;

  for (int i = tid; i < 32 * 69; i += 256) Wr1_s[i] = Wr1[i];
  const float hj = hbuf[(size_t)b * 64 + lane];
  h_s[w][lane] = hj;
  for (int idx = lane; idx < 100; idx += 64) cv_s[w][idx] = canvas[(size_t)b * 100 + idx];

  // act_tag: last token >= 1, check == 9
  const int t1 = inst[(size_t)b * TT + lane];
  const int t2 = inst[(size_t)b * TT + 64 + lane];
  int key = -1;
  if (t1 >= 1) key = (lane << 16) | t1;
  if (t2 >= 1) key = ((64 + lane) << 16) | t2;
#pragma unroll
  for (int s = 32; s; s >>= 1) key = max(key, __shfl_xor(key, s));
  const float tag = (key >= 0 && (key & 0xFFFF) == 9) ? 1.f : 0.f;

  __syncthreads();

  // hid[o] = relu(Wr1 @ feat + br1); h/tag part shared across the 25 slots
  const int o = lane & 31, half = lane >> 5;
  float base = br1[o] + Wr1_s[o * 69 + 64] * tag;
  for (int f = 0; f < 64; f++) base += Wr1_s[o * 69 + f] * h_s[w][f];
  const float wr2o = Wr2[o];
  const int n0 = half ? 13 : 0, n1 = half ? 25 : 13;
  for (int n = n0; n < n1; n++) {
    float acc = base;
#pragma unroll
    for (int d = 0; d < 4; d++) acc += Wr1_s[o * 69 + 65 + d] * cv_s[w][n * 4 + d];
    float p = wr2o * fmaxf(acc, 0.f);
#pragma unroll
    for (int s = 16; s; s >>= 1) p += __shfl_xor(p, s, 32);
    if (o == 0) sc_s[w][n] = p + br2[0];
  }
  __syncthreads();

  // softmax over 25 + weighted canvas rows 2,3 (redundant across lanes, cheap)
  float mx = -1e30f;
  for (int n = 0; n < 25; n++) mx = fmaxf(mx, sc_s[w][n]);
  float sum = 0.f, rp2 = 0.f, rp3 = 0.f;
  for (int n = 0; n < 25; n++) {
    float e = __expf(sc_s[w][n] - mx);
    sum += e;
    rp2 += e * cv_s[w][n * 4 + 2];
    rp3 += e * cv_s[w][n * 4 + 3];
  }
  const float inv = 1.f / sum;

  float c0 = wred64(hj * Wc[lane]),      c1 = wred64(hj * Wc[64 + lane]),  c2 = wred64(hj * Wc[128 + lane]);
  float s0 = wred64(hj * Ws[lane]),      s1 = wred64(hj * Ws[64 + lane]),  s2 = wred64(hj * Ws[128 + lane]);
  float o0 = wred64(hj * Wo[lane]),      o1 = wred64(hj * Wo[64 + lane]);
  c0 += bc[0]; c1 += bc[1]; c2 += bc[2];
  s0 += bs[0]; s1 += bs[1]; s2 += bs[2];
  o0 = fminf(fmaxf(o0 + bo[0], -1.f), 1.f);
  o1 = fminf(fmaxf(o1 + bo[1], -1.f), 1.f);

  const float cm = fmaxf(c0, fmaxf(c1, c2));
  const float cl = cm + __logf(__expf(c0 - cm) + __expf(c1 - cm) + __expf(c2 - cm));
  const float smx = fmaxf(s0, fmaxf(s1, s2));
  const float sl = smx + __logf(__expf(s0 - smx) + __expf(s1 - smx) + __expf(s2 - smx));

  if (lane == 0) {
    out[b * 3 + 0] = c0 - cl; out[b * 3 + 1] = c1 - cl; out[b * 3 + 2] = c2 - cl;
    float* shp = out + (size_t)3 * B;
    shp[b * 3 + 0] = s0 - sl; shp[b * 3 + 1] = s1 - sl; shp[b * 3 + 2] = s2 - sl;
    out[(size_t)6 * B + b] = rp2 * inv + o0;
    out[(size_t)7 * B + b] = rp3 * inv + o1;
  }
}

extern "C" void kernel_launch(void* const* d_in, const int* in_sizes, int n_in,
                              void* d_out, int out_size, void* d_ws, size_t ws_size,
                              hipStream_t stream) {
  const int*   inst   = (const int*)  d_in[0];
  const float* canvas = (const float*)d_in[1];
  // d_in[2] ref_obj, d_in[3] target_obj: unused by the reference outputs
  const float* embed  = (const float*)d_in[4];
  const float* Wih    = (const float*)d_in[5];
  const float* Whh    = (const float*)d_in[6];
  const float* bih    = (const float*)d_in[7];
  const float* bhh    = (const float*)d_in[8];
  const float* Wc     = (const float*)d_in[9];
  const float* bc     = (const float*)d_in[10];
  const float* Ws_    = (const float*)d_in[11];
  const float* bs     = (const float*)d_in[12];
  const float* Wo     = (const float*)d_in[13];
  const float* bo     = (const float*)d_in[14];
  const float* Wr1    = (const float*)d_in[15];
  const float* br1    = (const float*)d_in[16];
  const float* Wr2    = (const float*)d_in[17];
  const float* br2    = (const float*)d_in[18];

  const int B  = in_sizes[0] / TT;       // 4096
  const int NE = in_sizes[4];            // 32001 * 64

  unsigned short* ebf = (unsigned short*)d_ws;
  size_t ebytes = ((size_t)NE * 2 + 255) / 256 * 256;
  float* hbuf = (float*)((char*)d_ws + ebytes);

  convert_embed<<<(NE / 4 + 255) / 256, 256, 0, stream>>>(embed, ebf, NE);
  lstm_k<<<B / BT, 256, 0, stream>>>(inst, ebf, Wih, Whh, bih, bhh, hbuf);
  head_k<<<B / 4, 256, 0, stream>>>(inst, canvas, hbuf, Wc, bc, Ws_, bs, Wo, bo,
                                    Wr1, br1, Wr2, br2, (float*)d_out, B);
}